// Round 1
// baseline (1700.152 us; speedup 1.0000x reference)
//
#include <hip/hip_runtime.h>
#include <stdint.h>

// Keep float math un-fused so IoU bits match the numpy/JAX reference near the
// 0.6 / 0.3 mask thresholds.
#pragma clang fp contract(off)

#define BB 4
#define GG 64
#define AA 262144
#define TT 256
#define PP 128
#define NEG_THRESH 0.96875f   // exactly representable; expected ~8000 stored negs

// ---------------- Threefry-2x32 (matches jax._src.prng) ----------------
__host__ __device__ inline void tf2x32(uint32_t k0, uint32_t k1,
                                       uint32_t x0, uint32_t x1,
                                       uint32_t& o0, uint32_t& o1) {
  const uint32_t ks2 = k0 ^ k1 ^ 0x1BD11BDAu;
  x0 += k0; x1 += k1;
#define TF_R(r) { x0 += x1; x1 = (x1 << (r)) | (x1 >> (32 - (r))); x1 ^= x0; }
  TF_R(13) TF_R(15) TF_R(26) TF_R(6)
  x0 += k1;  x1 += ks2 + 1u;
  TF_R(17) TF_R(29) TF_R(16) TF_R(24)
  x0 += ks2; x1 += k0 + 2u;
  TF_R(13) TF_R(15) TF_R(26) TF_R(6)
  x0 += k0;  x1 += k1 + 3u;
  TF_R(17) TF_R(29) TF_R(16) TF_R(24)
  x0 += k1;  x1 += ks2 + 4u;
  TF_R(13) TF_R(15) TF_R(26) TF_R(6)
  x0 += ks2; x1 += k0 + 5u;
#undef TF_R
  o0 = x0; o1 = x1;
}

// jax.random.uniform bits, threefry_partitionable=True (default JAX >= 0.4.30):
// bits[i] = o0 ^ o1 of block(key, (hi32(i), lo32(i))); i < 2^32 here -> (0, i).
__device__ inline float tf_uniform(uint32_t k0, uint32_t k1, uint32_t idx) {
  uint32_t o0, o1;
  tf2x32(k0, k1, 0u, idx, o0, o1);
  uint32_t bits = o0 ^ o1;
  return __uint_as_float((bits >> 9) | 0x3f800000u) - 1.0f;
}

// ---------------- Kernel 1: IoU scan + classification + candidate store ----
__global__ __launch_bounds__(256) void k_scan(
    const float* __restrict__ gt_boxes,   // (B, G, 5)
    const float* __restrict__ gt_cls,     // (B, G, 3)
    const float* __restrict__ anchors,    // (B, A, 4)
    int* __restrict__ counters,           // per batch: npos, nneg, spos, sneg
    unsigned long long* __restrict__ pos_key,
    unsigned long long* __restrict__ neg_key,
    int* __restrict__ pos_gt,
    int cap_pos, int cap_neg,
    uint32_t kp0, uint32_t kp1, uint32_t kn0, uint32_t kn1) {
  __shared__ float4 s_gt[GG];
  __shared__ float  s_valid[GG];
  const int b = blockIdx.x >> 10;                    // A/256 = 1024 blocks/batch
  const int a = ((blockIdx.x & 1023) << 8) + threadIdx.x;
  if (threadIdx.x < GG) {
    const float* gb = gt_boxes + (size_t)(b * GG + threadIdx.x) * 5;
    s_gt[threadIdx.x] = make_float4(gb[0], gb[1], gb[2], gb[3]);
    s_valid[threadIdx.x] =
        (gt_cls[(size_t)(b * GG + threadIdx.x) * 3 + 2] != -1.0f) ? 1.f : 0.f;
  }
  __syncthreads();

  const float4 an = ((const float4*)anchors)[(size_t)b * AA + a];
  const float area_an = (an.w - an.y) * (an.z - an.x);
  float best = -1.0f;
  int bestg = 0;
  for (int g = 0; g < GG; ++g) {
    float4 gb = s_gt[g];
    float iw = fmaxf(0.f, fminf(gb.w, an.w) - fmaxf(gb.y, an.y));
    float ih = fmaxf(0.f, fminf(gb.z, an.z) - fmaxf(gb.x, an.x));
    float inter = iw * ih;
    float area_gt = (gb.w - gb.y) * (gb.z - gb.x);
    float iou = inter / (area_gt + area_an - inter);
    iou = (s_valid[g] != 0.f) ? iou : -1.0f;
    if (iou > best) { best = iou; bestg = g; }
  }

  const bool is_pos = best > 0.6f;
  const bool is_neg = best < 0.3f;

  // block-reduced counts (one atomic per wave per mask)
  unsigned long long mpos = __ballot(is_pos);
  unsigned long long mneg = __ballot(is_neg);
  if ((threadIdx.x & 63) == 0) {
    int cp = __popcll(mpos), cn = __popcll(mneg);
    if (cp) atomicAdd(&counters[b * 4 + 0], cp);
    if (cn) atomicAdd(&counters[b * 4 + 1], cn);
  }

  const uint32_t flat = (uint32_t)(b * AA + a);
  if (is_pos) {
    float pri = tf_uniform(kp0, kp1, flat);
    int slot = atomicAdd(&counters[b * 4 + 2], 1);
    if (slot < cap_pos) {
      unsigned long long key =
          ((unsigned long long)__float_as_uint(pri) << 32) | (uint32_t)(~(uint32_t)a);
      pos_key[(size_t)b * cap_pos + slot] = key;
      pos_gt[(size_t)b * cap_pos + slot] = bestg;
    }
  } else if (is_neg) {
    float pri = tf_uniform(kn0, kn1, flat);
    if (pri > NEG_THRESH) {
      int slot = atomicAdd(&counters[b * 4 + 3], 1);
      if (slot < cap_neg) {
        unsigned long long key =
            ((unsigned long long)__float_as_uint(pri) << 32) | (uint32_t)(~(uint32_t)a);
        neg_key[(size_t)b * cap_neg + slot] = key;
      }
    }
  }
}

// ---------------- Kernel 2: top-k selection + outputs ----------------------
// out layout (flat float32):
//   class_ids [0, 2048), deltas [2048, 6144), indices [6144, 8192),
//   gt_num [8192, 8196), pos_count [8196, 8200), miss [8200, 8204)
__global__ __launch_bounds__(256) void k_select(
    const float* __restrict__ gt_boxes,
    const float* __restrict__ gt_cls,
    const float* __restrict__ anchors,
    const int* __restrict__ counters,
    unsigned long long* __restrict__ pos_key,
    unsigned long long* __restrict__ neg_key,
    const int* __restrict__ pos_gt,
    int cap_pos, int cap_neg,
    float* __restrict__ out) {
  const int b = blockIdx.x;
  const int tid = threadIdx.x;

  __shared__ float4 s_gt[GG];
  __shared__ float s_cls0[GG], s_cls1[GG];
  __shared__ int s_valid[GG];
  __shared__ int sel_idx[TT];
  __shared__ int sel_gt[TT];
  __shared__ unsigned long long red_key[256];
  __shared__ int red_pos[256];
  __shared__ unsigned int hit_lo, hit_hi;

  if (tid < GG) {
    const float* gb = gt_boxes + (size_t)(b * GG + tid) * 5;
    s_gt[tid] = make_float4(gb[0], gb[1], gb[2], gb[3]);
    s_cls0[tid] = gt_cls[(size_t)(b * GG + tid) * 3 + 0];
    s_cls1[tid] = gt_cls[(size_t)(b * GG + tid) * 3 + 1];
    s_valid[tid] = (gt_cls[(size_t)(b * GG + tid) * 3 + 2] != -1.0f) ? 1 : 0;
  }
  if (tid == 0) { hit_lo = 0u; hit_hi = 0u; }
  __syncthreads();

  const int npos = counters[b * 4 + 0];
  const int nneg = counters[b * 4 + 1];
  const int spos = min(counters[b * 4 + 2], cap_pos);
  const int sneg = min(counters[b * 4 + 3], cap_neg);
  int pos_count = min(PP, npos);
  pos_count = min(pos_count, spos);           // safety (spos==npos in practice)
  int neg_count = min(TT - pos_count, nneg);
  neg_count = min(neg_count, sneg);           // safety (sneg >> 256 in practice)

  // --- iterative parallel arg-max extraction: positives then negatives ---
  for (int phase = 0; phase < 2; ++phase) {
    unsigned long long* keys =
        phase == 0 ? pos_key + (size_t)b * cap_pos : neg_key + (size_t)b * cap_neg;
    const int m = phase == 0 ? spos : sneg;
    const int k = phase == 0 ? pos_count : neg_count;
    const int sel_base = phase == 0 ? 0 : pos_count;
    for (int r = 0; r < k; ++r) {
      unsigned long long bk = 0ull;
      int bp = -1;
      for (int i = tid; i < m; i += 256) {
        unsigned long long kk = keys[i];
        if (kk > bk) { bk = kk; bp = i; }
      }
      red_key[tid] = bk;
      red_pos[tid] = bp;
      __syncthreads();
      for (int s = 128; s > 0; s >>= 1) {
        if (tid < s && red_key[tid + s] > red_key[tid]) {
          red_key[tid] = red_key[tid + s];
          red_pos[tid] = red_pos[tid + s];
        }
        __syncthreads();
      }
      if (tid == 0) {
        int p = red_pos[0];
        sel_idx[sel_base + r] = (int)(~(uint32_t)(red_key[0] & 0xFFFFFFFFull));
        if (phase == 0) sel_gt[sel_base + r] = pos_gt[(size_t)b * cap_pos + p];
        keys[p] = 0ull;  // mark used
      }
      __syncthreads();
    }
  }

  // --- per-slot outputs ---
  const int j = tid;  // T == 256 == blockDim
  const bool isp = j < pos_count;
  const bool isn = (j >= pos_count) && (j < pos_count + neg_count);
  float c0 = 0.f, c1 = 0.f, d0 = 0.f, d1 = 0.f, d2 = 0.f, d3 = 0.f;
  int out_idx = -1, tag = -1;
  if (isp) {
    int aidx = sel_idx[j];
    int g = sel_gt[j];
    out_idx = aidx; tag = 1;
    c0 = s_cls0[g]; c1 = s_cls1[g];
    float4 an = ((const float4*)anchors)[(size_t)b * AA + aidx];
    float4 gb = s_gt[g];
    float h = an.z - an.x, w = an.w - an.y;
    float gh = gb.z - gb.x, gw = gb.w - gb.y;
    float cy = (an.z + an.x) * 0.5f, cx = (an.w + an.y) * 0.5f;
    float gcy = (gb.z + gb.x) * 0.5f, gcx = (gb.w + gb.y) * 0.5f;
    d0 = ((gcy - cy) / h) / 0.1f;
    d1 = ((gcx - cx) / w) / 0.1f;
    d2 = logf(gh / h) / 0.2f;
    d3 = logf(gw / w) / 0.2f;
    if (g < 32) atomicOr(&hit_lo, 1u << g);
    else        atomicOr(&hit_hi, 1u << (g - 32));
  } else if (isn) {
    out_idx = sel_idx[j]; tag = 0;
    c0 = 1.f; c1 = 0.f;
  }

  float* cls_out = out + ((size_t)b * TT + j) * 2;
  cls_out[0] = c0; cls_out[1] = c1;
  float* del_out = out + 2048 + ((size_t)b * TT + j) * 4;
  del_out[0] = d0; del_out[1] = d1; del_out[2] = d2; del_out[3] = d3;
  float* idx_out = out + 6144 + ((size_t)b * TT + j) * 2;
  idx_out[0] = (float)out_idx; idx_out[1] = (float)tag;

  __syncthreads();
  if (tid == 0) {
    int gn = 0;
    for (int g = 0; g < GG; ++g) gn += s_valid[g];
    float hits = (float)(__popc(hit_lo) + __popc(hit_hi));
    out[8192 + b] = (float)gn;
    out[8196 + b] = (float)pos_count;
    out[8200 + b] = (float)gn - hits;
  }
}

// ---------------- host ----------------
extern "C" void kernel_launch(void* const* d_in, const int* in_sizes, int n_in,
                              void* d_out, int out_size, void* d_ws, size_t ws_size,
                              hipStream_t stream) {
  const float* gt_boxes = (const float*)d_in[0];
  const float* gt_cls   = (const float*)d_in[1];
  const float* anchors  = (const float*)d_in[2];
  float* out = (float*)d_out;

  // folded keys: key(42) = (0,42); fold_in(k, d) = threefry block on (0, d)
  uint32_t kp0, kp1, kn0, kn1;
  tf2x32(0u, 42u, 0u, 0u, kp0, kp1);   // pri_pos key
  tf2x32(0u, 42u, 0u, 1u, kn0, kn1);   // pri_neg key

  // ws layout: [256B counters][pos_key B*cap_pos*8][neg_key B*cap_neg*8][pos_gt B*cap_pos*4]
  long cap_pos = 65536, cap_neg = 32768;
  size_t avail = ws_size > 256 ? ws_size - 256 : 0;
  while (cap_pos > 512 &&
         (size_t)BB * ((size_t)cap_pos * 12 + (size_t)cap_neg * 8) > avail) {
    cap_pos >>= 1; cap_neg >>= 1;
  }
  char* base = (char*)d_ws;
  int* counters = (int*)base;
  unsigned long long* pos_key = (unsigned long long*)(base + 256);
  unsigned long long* neg_key = pos_key + (size_t)BB * cap_pos;
  int* pos_gt = (int*)(neg_key + (size_t)BB * cap_neg);

  hipMemsetAsync(d_ws, 0, 256, stream);
  k_scan<<<BB * (AA / 256), 256, 0, stream>>>(
      gt_boxes, gt_cls, anchors, counters, pos_key, neg_key, pos_gt,
      (int)cap_pos, (int)cap_neg, kp0, kp1, kn0, kn1);
  k_select<<<BB, 256, 0, stream>>>(
      gt_boxes, gt_cls, anchors, counters, pos_key, neg_key, pos_gt,
      (int)cap_pos, (int)cap_neg, out);
}

// Round 3
// 465.783 us; speedup vs baseline: 3.6501x; 3.6501x over previous
//
#include <hip/hip_runtime.h>
#include <stdint.h>

// Keep float math un-fused so IoU bits match the numpy/JAX reference near the
// 0.6 / 0.3 mask thresholds.
#pragma clang fp contract(off)

#define BB 4
#define GG 64
#define AA 262144
#define TT 256
#define PP 128
#define APT 2                 // anchors per thread in k_scan
#define NEG_THRESH 0.99f      // stored negs ~2600; top-256 boundary ~0.9988
#define NBINS 2048
#define CANDCAP 1024
#define NT_SEL 512

// ---------------- Threefry-2x32 (matches jax._src.prng) ----------------
__host__ __device__ inline void tf2x32(uint32_t k0, uint32_t k1,
                                       uint32_t x0, uint32_t x1,
                                       uint32_t& o0, uint32_t& o1) {
  const uint32_t ks2 = k0 ^ k1 ^ 0x1BD11BDAu;
  x0 += k0; x1 += k1;
#define TF_R(r) { x0 += x1; x1 = (x1 << (r)) | (x1 >> (32 - (r))); x1 ^= x0; }
  TF_R(13) TF_R(15) TF_R(26) TF_R(6)
  x0 += k1;  x1 += ks2 + 1u;
  TF_R(17) TF_R(29) TF_R(16) TF_R(24)
  x0 += ks2; x1 += k0 + 2u;
  TF_R(13) TF_R(15) TF_R(26) TF_R(6)
  x0 += k0;  x1 += k1 + 3u;
  TF_R(17) TF_R(29) TF_R(16) TF_R(24)
  x0 += k1;  x1 += ks2 + 4u;
  TF_R(13) TF_R(15) TF_R(26) TF_R(6)
  x0 += ks2; x1 += k0 + 5u;
#undef TF_R
  o0 = x0; o1 = x1;
}

// jax.random.uniform, threefry_partitionable path: bits[i] = o0^o1 of
// block(key, (0, i)); value = bitcast((bits>>9)|0x3f800000) - 1.0
__device__ inline float tf_uniform(uint32_t k0, uint32_t k1, uint32_t idx) {
  uint32_t o0, o1;
  tf2x32(k0, k1, 0u, idx, o0, o1);
  uint32_t bits = o0 ^ o1;
  return __uint_as_float((bits >> 9) | 0x3f800000u) - 1.0f;
}

// key layout: [63:32] priority float bits, [23:6] ~a (18 bits), [5:0] gt idx.
// Desc sort == JAX top_k order (value desc, index asc); a unique -> g bits
// never decide order.
__device__ inline unsigned long long make_key(float pri, int a, int g) {
  const uint32_t inv = (uint32_t)a ^ 0x3FFFFu;
  return ((unsigned long long)__float_as_uint(pri) << 32) |
         ((unsigned long long)inv << 6) | (unsigned)g;
}

// ---------------- Kernel 1: IoU scan + classification + candidate store ----
__global__ __launch_bounds__(256) void k_scan(
    const float* __restrict__ gt_boxes,   // (B, G, 5)
    const float* __restrict__ gt_cls,     // (B, G, 3)
    const float* __restrict__ anchors,    // (B, A, 4)
    int* __restrict__ counters,           // per batch: npos, nneg, spos, sneg
    unsigned long long* __restrict__ pos_key,
    unsigned long long* __restrict__ neg_key,
    int cap_pos, int cap_neg,
    uint32_t kp0, uint32_t kp1, uint32_t kn0, uint32_t kn1) {
  __shared__ float4 s_gt[GG];
  const int BPB = AA / (256 * APT);                  // blocks per batch = 512
  const int b = blockIdx.x / BPB;
  const int base = (blockIdx.x % BPB) * (256 * APT);
  const int tid = threadIdx.x;
  if (tid < GG) {
    const float* gb = gt_boxes + (size_t)(b * GG + tid) * 5;
    // invalid gt -> zero box: IoU == +0.0 exactly, which can't flip
    // pos (>0.6) / neg (<0.3) and can't win argmax (valid gts precede and
    // every iou >= 0, comparison strict >).
    bool v = gt_cls[(size_t)(b * GG + tid) * 3 + 2] != -1.0f;
    s_gt[tid] = v ? make_float4(gb[0], gb[1], gb[2], gb[3])
                  : make_float4(0.f, 0.f, 0.f, 0.f);
  }
  __syncthreads();

  float4 an[APT];
  float area_an[APT], best[APT];
  int bestg[APT];
  const float4* ap = (const float4*)anchors + (size_t)b * AA + base + tid;
#pragma unroll
  for (int k = 0; k < APT; ++k) {
    an[k] = ap[k * 256];
    area_an[k] = (an[k].w - an[k].y) * (an[k].z - an[k].x);
    best[k] = -1.0f;
    bestg[k] = 0;
  }
  for (int g = 0; g < GG; ++g) {
    const float4 gb = s_gt[g];
    const float area_gt = (gb.w - gb.y) * (gb.z - gb.x);
#pragma unroll
    for (int k = 0; k < APT; ++k) {
      float iw = fmaxf(0.f, fminf(gb.w, an[k].w) - fmaxf(gb.y, an[k].y));
      float ih = fmaxf(0.f, fminf(gb.z, an[k].z) - fmaxf(gb.x, an[k].x));
      float inter = iw * ih;
      float iou = inter / (area_gt + area_an[k] - inter);
      if (iou > best[k]) { best[k] = iou; bestg[k] = g; }
    }
  }

  int cp = 0, cn = 0;
  bool isp[APT], isn[APT];
#pragma unroll
  for (int k = 0; k < APT; ++k) {
    isp[k] = best[k] > 0.6f;
    isn[k] = best[k] < 0.3f;
    cp += __popcll(__ballot(isp[k]));
    cn += __popcll(__ballot(isn[k]));
  }
  if ((tid & 63) == 0) {
    if (cp) atomicAdd(&counters[b * 4 + 0], cp);
    if (cn) atomicAdd(&counters[b * 4 + 1], cn);
  }

#pragma unroll
  for (int k = 0; k < APT; ++k) {
    const int a = base + k * 256 + tid;
    const uint32_t flat = (uint32_t)(b * AA + a);
    if (isp[k]) {
      float pri = tf_uniform(kp0, kp1, flat);
      int slot = atomicAdd(&counters[b * 4 + 2], 1);
      if (slot < cap_pos)
        pos_key[(size_t)b * cap_pos + slot] = make_key(pri, a, bestg[k]);
    } else if (isn[k]) {
      float pri = tf_uniform(kn0, kn1, flat);
      if (pri > NEG_THRESH) {
        int slot = atomicAdd(&counters[b * 4 + 3], 1);
        if (slot < cap_neg)
          neg_key[(size_t)b * cap_neg + slot] = make_key(pri, a, 0);
      }
    }
  }
}

// ---------------- bitonic sort (descending) over CANDCAP u64 keys ----------
__device__ inline void bitonic1024_desc(unsigned long long* buf, int tid) {
  for (unsigned k = 2; k <= CANDCAP; k <<= 1) {
    for (unsigned s = k >> 1; s > 0; s >>= 1) {
      __syncthreads();
      for (unsigned i = tid; i < CANDCAP; i += NT_SEL) {
        unsigned p = i ^ s;
        if (p > i) {
          unsigned long long x = buf[i], y = buf[p];
          if (((i & k) == 0) ? (x < y) : (x > y)) { buf[i] = y; buf[p] = x; }
        }
      }
    }
  }
  __syncthreads();
}

// ---------------- Kernel 2: exact histogram top-k + outputs ----------------
// out layout (flat float32):
//   class_ids [0, 2048), deltas [2048, 6144), indices [6144, 8192),
//   gt_num [8192, 8196), pos_count [8196, 8200), miss [8200, 8204)
__global__ __launch_bounds__(NT_SEL) void k_select(
    const float* __restrict__ gt_boxes,
    const float* __restrict__ gt_cls,
    const float* __restrict__ anchors,
    const int* __restrict__ counters,
    const unsigned long long* __restrict__ pos_key,
    const unsigned long long* __restrict__ neg_key,
    int cap_pos, int cap_neg,
    float* __restrict__ out) {
  const int b = blockIdx.x;
  const int tid = threadIdx.x;

  __shared__ int hist[NBINS];
  __shared__ unsigned long long cand[CANDCAP];
  __shared__ unsigned long long sel[TT];
  __shared__ float4 s_gt[GG];
  __shared__ float s_cls0[GG], s_cls1[GG];
  __shared__ int s_valid[GG];
  __shared__ unsigned int hit_lo, hit_hi;
  __shared__ int s_t, s_cnt;

  if (tid < GG) {
    const float* gb = gt_boxes + (size_t)(b * GG + tid) * 5;
    s_gt[tid] = make_float4(gb[0], gb[1], gb[2], gb[3]);
    s_cls0[tid] = gt_cls[(size_t)(b * GG + tid) * 3 + 0];
    s_cls1[tid] = gt_cls[(size_t)(b * GG + tid) * 3 + 1];
    s_valid[tid] = (gt_cls[(size_t)(b * GG + tid) * 3 + 2] != -1.0f) ? 1 : 0;
  }
  if (tid == 0) { hit_lo = 0u; hit_hi = 0u; }

  const int npos = counters[b * 4 + 0];
  const int nneg = counters[b * 4 + 1];
  const int sp = min(counters[b * 4 + 2], cap_pos);
  const int sn = min(counters[b * 4 + 3], cap_neg);
  int pos_count = min(min(PP, npos), sp);
  int neg_count = min(min(TT - pos_count, nneg), sn);

  // --- exact top-k per phase: histogram threshold + small sort ---
  for (int phase = 0; phase < 2; ++phase) {
    const unsigned long long* keys =
        phase ? neg_key + (size_t)b * cap_neg : pos_key + (size_t)b * cap_pos;
    const int n = phase ? sn : sp;
    const int kk = phase ? neg_count : pos_count;
    const int sbase = phase ? pos_count : 0;

    for (int i = tid; i < NBINS; i += NT_SEL) hist[i] = 0;
    if (tid == 0) s_cnt = 0;
    __syncthreads();

    for (int i = tid; i < n; i += NT_SEL) {
      float pri = __uint_as_float((uint32_t)(keys[i] >> 32));
      int bin = min(NBINS - 1, (int)(pri * (float)NBINS));
      atomicAdd(&hist[bin], 1);
    }
    __syncthreads();

    if (tid == 0) {
      int t = 0;
      if (kk == 0) {
        t = NBINS;                       // collect nothing
      } else {
        int acc = 0;
        for (int bb = NBINS - 1; bb >= 0; --bb) {
          acc += hist[bb];
          if (acc >= kk) { t = bb; break; }
        }
        // if acc < kk (n < kk): t stays 0 -> collect all n (n < kk <= 256)
      }
      s_t = t;
    }
    __syncthreads();
    const int t = s_t;

    for (int i = tid; i < n; i += NT_SEL) {
      unsigned long long key = keys[i];
      float pri = __uint_as_float((uint32_t)(key >> 32));
      int bin = min(NBINS - 1, (int)(pri * (float)NBINS));
      if (bin >= t) {
        int slot = atomicAdd(&s_cnt, 1);
        if (slot < CANDCAP) cand[slot] = key;
      }
    }
    __syncthreads();
    const int cnt = min(s_cnt, CANDCAP);
    for (int i = tid; i < CANDCAP; i += NT_SEL)
      if (i >= cnt) cand[i] = 0ull;
    bitonic1024_desc(cand, tid);       // starts with its own __syncthreads
    for (int i = tid; i < kk; i += NT_SEL) sel[sbase + i] = cand[i];
    __syncthreads();
  }

  // --- per-slot outputs ---
  if (tid < TT) {
    const int j = tid;
    const bool isp = j < pos_count;
    const bool isn = !isp && (j < pos_count + neg_count);
    float c0 = 0.f, c1 = 0.f, d0 = 0.f, d1 = 0.f, d2 = 0.f, d3 = 0.f;
    int out_idx = -1, tag = -1;
    if (isp) {
      const unsigned long long key = sel[j];
      const int a = (int)((((unsigned)(key >> 6)) & 0x3FFFFu) ^ 0x3FFFFu);
      const int g = (int)(key & 63ull);
      out_idx = a; tag = 1;
      c0 = s_cls0[g]; c1 = s_cls1[g];
      float4 an = ((const float4*)anchors)[(size_t)b * AA + a];
      float4 gb = s_gt[g];
      float h = an.z - an.x, w = an.w - an.y;
      float gh = gb.z - gb.x, gw = gb.w - gb.y;
      float cy = (an.z + an.x) * 0.5f, cx = (an.w + an.y) * 0.5f;
      float gcy = (gb.z + gb.x) * 0.5f, gcx = (gb.w + gb.y) * 0.5f;
      d0 = ((gcy - cy) / h) / 0.1f;
      d1 = ((gcx - cx) / w) / 0.1f;
      d2 = logf(gh / h) / 0.2f;
      d3 = logf(gw / w) / 0.2f;
      if (g < 32) atomicOr(&hit_lo, 1u << g);
      else        atomicOr(&hit_hi, 1u << (g - 32));
    } else if (isn) {
      const unsigned long long key = sel[j];
      out_idx = (int)((((unsigned)(key >> 6)) & 0x3FFFFu) ^ 0x3FFFFu);
      tag = 0;
      c0 = 1.f; c1 = 0.f;
    }

    float* cls_out = out + ((size_t)b * TT + j) * 2;
    cls_out[0] = c0; cls_out[1] = c1;
    float* del_out = out + 2048 + ((size_t)b * TT + j) * 4;
    del_out[0] = d0; del_out[1] = d1; del_out[2] = d2; del_out[3] = d3;
    float* idx_out = out + 6144 + ((size_t)b * TT + j) * 2;
    idx_out[0] = (float)out_idx; idx_out[1] = (float)tag;
  }

  __syncthreads();
  if (tid == 0) {
    int gn = 0;
    for (int g = 0; g < GG; ++g) gn += s_valid[g];
    float hits = (float)(__popc(hit_lo) + __popc(hit_hi));
    out[8192 + b] = (float)gn;
    out[8196 + b] = (float)pos_count;
    out[8200 + b] = (float)gn - hits;
  }
}

// ---------------- host ----------------
extern "C" void kernel_launch(void* const* d_in, const int* in_sizes, int n_in,
                              void* d_out, int out_size, void* d_ws, size_t ws_size,
                              hipStream_t stream) {
  const float* gt_boxes = (const float*)d_in[0];
  const float* gt_cls   = (const float*)d_in[1];
  const float* anchors  = (const float*)d_in[2];
  float* out = (float*)d_out;

  // folded keys: key(42) = (0,42); fold_in(k, d) = threefry block on (0, d)
  uint32_t kp0, kp1, kn0, kn1;
  tf2x32(0u, 42u, 0u, 0u, kp0, kp1);   // pri_pos key
  tf2x32(0u, 42u, 0u, 1u, kn0, kn1);   // pri_neg key

  // ws layout: [256B counters][pos_key B*cap_pos*8][neg_key B*cap_neg*8]
  long cap_pos = 32768, cap_neg = 8192;
  while (cap_pos > 2048 &&
         256 + (size_t)BB * 8 * (size_t)(cap_pos + cap_neg) > ws_size) {
    cap_pos >>= 1; cap_neg >>= 1;
  }
  char* base = (char*)d_ws;
  int* counters = (int*)base;
  unsigned long long* pos_key = (unsigned long long*)(base + 256);
  unsigned long long* neg_key = pos_key + (size_t)BB * cap_pos;

  hipMemsetAsync(d_ws, 0, 256, stream);
  k_scan<<<BB * (AA / (256 * APT)), 256, 0, stream>>>(
      gt_boxes, gt_cls, anchors, counters, pos_key, neg_key,
      (int)cap_pos, (int)cap_neg, kp0, kp1, kn0, kn1);
  k_select<<<BB, NT_SEL, 0, stream>>>(
      gt_boxes, gt_cls, anchors, counters, pos_key, neg_key,
      (int)cap_pos, (int)cap_neg, out);
}

// Round 5
// 126.427 us; speedup vs baseline: 13.4476x; 3.6842x over previous
//
#include <hip/hip_runtime.h>
#include <stdint.h>

// Keep float math un-fused so IoU bits match the numpy/JAX reference near the
// 0.6 / 0.3 mask thresholds.
#pragma clang fp contract(off)

#define BB 4
#define GG 64
#define AA 262144
#define TT 256
#define PP 128
#define APT 4                 // anchors per thread in k_scan
#define NEG_THRESH 0.99f      // stored negs ~2600/batch; top-256 boundary ~0.9988
#define NBINS 2048
#define CANDCAP 1024
#define NT_SEL 512
#define SCAN_NT 256
#define BLK_ANCH (SCAN_NT * APT)   // 1024 anchors per block

// ---------------- Threefry-2x32 (matches jax._src.prng) ----------------
__host__ __device__ inline void tf2x32(uint32_t k0, uint32_t k1,
                                       uint32_t x0, uint32_t x1,
                                       uint32_t& o0, uint32_t& o1) {
  const uint32_t ks2 = k0 ^ k1 ^ 0x1BD11BDAu;
  x0 += k0; x1 += k1;
#define TF_R(r) { x0 += x1; x1 = (x1 << (r)) | (x1 >> (32 - (r))); x1 ^= x0; }
  TF_R(13) TF_R(15) TF_R(26) TF_R(6)
  x0 += k1;  x1 += ks2 + 1u;
  TF_R(17) TF_R(29) TF_R(16) TF_R(24)
  x0 += ks2; x1 += k0 + 2u;
  TF_R(13) TF_R(15) TF_R(26) TF_R(6)
  x0 += k0;  x1 += k1 + 3u;
  TF_R(17) TF_R(29) TF_R(16) TF_R(24)
  x0 += k1;  x1 += ks2 + 4u;
  TF_R(13) TF_R(15) TF_R(26) TF_R(6)
  x0 += ks2; x1 += k0 + 5u;
#undef TF_R
  o0 = x0; o1 = x1;
}

// jax.random.uniform, threefry_partitionable path: bits[i] = o0^o1 of
// block(key, (0, i)); value = bitcast((bits>>9)|0x3f800000) - 1.0
__device__ inline float tf_uniform(uint32_t k0, uint32_t k1, uint32_t idx) {
  uint32_t o0, o1;
  tf2x32(k0, k1, 0u, idx, o0, o1);
  uint32_t bits = o0 ^ o1;
  return __uint_as_float((bits >> 9) | 0x3f800000u) - 1.0f;
}

// key layout: [63:32] priority float bits, [23:6] ~a (18 bits), [5:0] gt idx.
// Desc sort == JAX top_k order (value desc, index asc); a unique -> g bits
// never decide order.
__device__ inline unsigned long long make_key(float pri, int a, int g) {
  const uint32_t inv = (uint32_t)a ^ 0x3FFFFu;
  return ((unsigned long long)__float_as_uint(pri) << 32) |
         ((unsigned long long)inv << 6) | (unsigned)g;
}

// ---------------- Kernel 1: IoU scan + block-aggregated candidate store ----
__global__ __launch_bounds__(SCAN_NT) void k_scan(
    const float* __restrict__ gt_boxes,   // (B, G, 5)
    const float* __restrict__ gt_cls,     // (B, G, 3)
    const float* __restrict__ anchors,    // (B, A, 4)
    int* __restrict__ counters,           // per batch: npos, nneg, spos, sneg
    unsigned long long* __restrict__ pos_key,
    unsigned long long* __restrict__ neg_key,
    int cap_pos, int cap_neg,
    uint32_t kp0, uint32_t kp1, uint32_t kn0, uint32_t kn1) {
  __shared__ float4 s_gt[GG];
  __shared__ unsigned long long l_pos[BLK_ANCH];
  __shared__ unsigned long long l_neg[BLK_ANCH];
  __shared__ int l_cnt[4];     // pos stored, neg stored, npos, nneg
  __shared__ int l_base[2];

  const int BPB = AA / BLK_ANCH;                     // blocks per batch = 256
  const int b = blockIdx.x / BPB;
  const int base = (blockIdx.x % BPB) * BLK_ANCH;
  const int tid = threadIdx.x;
  const int lane = tid & 63;
  const unsigned long long below = (lane == 0) ? 0ull : (~0ull >> (64 - lane));

  if (tid < GG) {
    const float* gb = gt_boxes + (size_t)(b * GG + tid) * 5;
    // invalid gt -> zero box: IoU == +0.0 exactly, which can't flip
    // pos (>0.6) / neg (<0.3) and can't win argmax (strict >, iou >= 0).
    bool v = gt_cls[(size_t)(b * GG + tid) * 3 + 2] != -1.0f;
    s_gt[tid] = v ? make_float4(gb[0], gb[1], gb[2], gb[3])
                  : make_float4(0.f, 0.f, 0.f, 0.f);
  }
  if (tid < 4) l_cnt[tid] = 0;
  __syncthreads();

  float4 an[APT];
  float area_an[APT], best[APT];
  int bestg[APT];
  const float4* ap = (const float4*)anchors + (size_t)b * AA + base + tid;
#pragma unroll
  for (int k = 0; k < APT; ++k) {
    an[k] = ap[k * SCAN_NT];
    area_an[k] = (an[k].w - an[k].y) * (an[k].z - an[k].x);
    best[k] = -1.0f;
    bestg[k] = 0;
  }
  for (int g = 0; g < GG; ++g) {
    const float4 gb = s_gt[g];
    const float area_gt = (gb.w - gb.y) * (gb.z - gb.x);
#pragma unroll
    for (int k = 0; k < APT; ++k) {
      float iw = fmaxf(0.f, fminf(gb.w, an[k].w) - fmaxf(gb.y, an[k].y));
      float ih = fmaxf(0.f, fminf(gb.z, an[k].z) - fmaxf(gb.x, an[k].x));
      float inter = iw * ih;
      float iou = inter / (area_gt + area_an[k] - inter);
      if (iou > best[k]) { best[k] = iou; bestg[k] = g; }
    }
  }

  // classify + stage candidates in LDS.
  // ALL ballots/shfls/leader-atomics execute at full-wave convergence;
  // only the LDS store itself is predicated (round-4 bug: leader atomic
  // inside the divergent branch -> shfl from inactive lane = garbage).
#pragma unroll
  for (int k = 0; k < APT; ++k) {
    const int a = base + k * SCAN_NT + tid;
    const uint32_t flat = (uint32_t)(b * AA + a);
    const bool isp = best[k] > 0.6f;
    const bool isn = best[k] < 0.3f;

    float prin = 0.f;
    bool store_n = false;
    if (isn) {
      prin = tf_uniform(kn0, kn1, flat);
      store_n = prin > NEG_THRESH;
    }

    const unsigned long long mp = __ballot(isp);
    const unsigned long long mnAll = __ballot(isn);
    const unsigned long long mn = __ballot(store_n);

    int wbase_p = 0, wbase_n = 0;
    if (lane == 0) {
      const int cp = __popcll(mp);
      const int cs = __popcll(mn);
      const int cnAll = __popcll(mnAll);
      if (cp) { wbase_p = atomicAdd(&l_cnt[0], cp); atomicAdd(&l_cnt[2], cp); }
      if (cs) wbase_n = atomicAdd(&l_cnt[1], cs);
      if (cnAll) atomicAdd(&l_cnt[3], cnAll);
    }
    wbase_p = __shfl(wbase_p, 0);
    wbase_n = __shfl(wbase_n, 0);

    if (isp) {
      float pri = tf_uniform(kp0, kp1, flat);
      l_pos[wbase_p + __popcll(mp & below)] = make_key(pri, a, bestg[k]);
    }
    if (store_n) {
      l_neg[wbase_n + __popcll(mn & below)] = make_key(prin, a, 0);
    }
  }
  __syncthreads();

  // one returning device atomic per non-empty list per block
  if (tid == 0) {
    l_base[0] = l_cnt[0] ? atomicAdd(&counters[b * 4 + 2], l_cnt[0]) : 0;
    if (l_cnt[2]) atomicAdd(&counters[b * 4 + 0], l_cnt[2]);
  } else if (tid == 64) {
    l_base[1] = l_cnt[1] ? atomicAdd(&counters[b * 4 + 3], l_cnt[1]) : 0;
    if (l_cnt[3]) atomicAdd(&counters[b * 4 + 1], l_cnt[3]);
  }
  __syncthreads();

  // coalesced copy-out (prefix [0,cap) stays fully populated: a straddling
  // block writes only its in-range part, so k_select's min(counter, cap)
  // prefix is complete; selection is order-independent)
  for (int i = tid; i < l_cnt[0]; i += SCAN_NT) {
    int dst = l_base[0] + i;
    if (dst < cap_pos) pos_key[(size_t)b * cap_pos + dst] = l_pos[i];
  }
  for (int i = tid; i < l_cnt[1]; i += SCAN_NT) {
    int dst = l_base[1] + i;
    if (dst < cap_neg) neg_key[(size_t)b * cap_neg + dst] = l_neg[i];
  }
}

// ---------------- bitonic sort (descending) over CANDCAP u64 keys ----------
__device__ inline void bitonic1024_desc(unsigned long long* buf, int tid) {
  for (unsigned k = 2; k <= CANDCAP; k <<= 1) {
    for (unsigned s = k >> 1; s > 0; s >>= 1) {
      __syncthreads();
      for (unsigned i = tid; i < CANDCAP; i += NT_SEL) {
        unsigned p = i ^ s;
        if (p > i) {
          unsigned long long x = buf[i], y = buf[p];
          if (((i & k) == 0) ? (x < y) : (x > y)) { buf[i] = y; buf[p] = x; }
        }
      }
    }
  }
  __syncthreads();
}

// ---------------- Kernel 2: exact histogram top-k + outputs ----------------
// out layout (flat float32):
//   class_ids [0, 2048), deltas [2048, 6144), indices [6144, 8192),
//   gt_num [8192, 8196), pos_count [8196, 8200), miss [8200, 8204)
__global__ __launch_bounds__(NT_SEL) void k_select(
    const float* __restrict__ gt_boxes,
    const float* __restrict__ gt_cls,
    const float* __restrict__ anchors,
    const int* __restrict__ counters,
    const unsigned long long* __restrict__ pos_key,
    const unsigned long long* __restrict__ neg_key,
    int cap_pos, int cap_neg,
    float* __restrict__ out) {
  const int b = blockIdx.x;
  const int tid = threadIdx.x;

  __shared__ int hist[NBINS];
  __shared__ unsigned long long cand[CANDCAP];
  __shared__ unsigned long long sel[TT];
  __shared__ float4 s_gt[GG];
  __shared__ float s_cls0[GG], s_cls1[GG];
  __shared__ int s_valid[GG];
  __shared__ unsigned int hit_lo, hit_hi;
  __shared__ int s_t, s_cnt;

  if (tid < GG) {
    const float* gb = gt_boxes + (size_t)(b * GG + tid) * 5;
    s_gt[tid] = make_float4(gb[0], gb[1], gb[2], gb[3]);
    s_cls0[tid] = gt_cls[(size_t)(b * GG + tid) * 3 + 0];
    s_cls1[tid] = gt_cls[(size_t)(b * GG + tid) * 3 + 1];
    s_valid[tid] = (gt_cls[(size_t)(b * GG + tid) * 3 + 2] != -1.0f) ? 1 : 0;
  }
  if (tid == 0) { hit_lo = 0u; hit_hi = 0u; }

  const int npos = counters[b * 4 + 0];
  const int nneg = counters[b * 4 + 1];
  const int sp = min(counters[b * 4 + 2], cap_pos);
  const int sn = min(counters[b * 4 + 3], cap_neg);
  int pos_count = min(min(PP, npos), sp);
  int neg_count = min(min(TT - pos_count, nneg), sn);

  // --- exact top-k per phase: histogram threshold + small sort ---
  for (int phase = 0; phase < 2; ++phase) {
    const unsigned long long* keys =
        phase ? neg_key + (size_t)b * cap_neg : pos_key + (size_t)b * cap_pos;
    const int n = phase ? sn : sp;
    const int kk = phase ? neg_count : pos_count;
    const int sbase = phase ? pos_count : 0;

    for (int i = tid; i < NBINS; i += NT_SEL) hist[i] = 0;
    if (tid == 0) s_cnt = 0;
    __syncthreads();

    for (int i = tid; i < n; i += NT_SEL) {
      float pri = __uint_as_float((uint32_t)(keys[i] >> 32));
      int bin = min(NBINS - 1, (int)(pri * (float)NBINS));
      atomicAdd(&hist[bin], 1);
    }
    __syncthreads();

    if (tid == 0) {
      int t = 0;
      if (kk == 0) {
        t = NBINS;                       // collect nothing
      } else {
        int acc = 0;
        for (int bb = NBINS - 1; bb >= 0; --bb) {
          acc += hist[bb];
          if (acc >= kk) { t = bb; break; }
        }
        // if acc < kk (n < kk): t stays 0 -> collect all n (n < kk <= 256)
      }
      s_t = t;
    }
    __syncthreads();
    const int t = s_t;

    for (int i = tid; i < n; i += NT_SEL) {
      unsigned long long key = keys[i];
      float pri = __uint_as_float((uint32_t)(key >> 32));
      int bin = min(NBINS - 1, (int)(pri * (float)NBINS));
      if (bin >= t) {
        int slot = atomicAdd(&s_cnt, 1);
        if (slot < CANDCAP) cand[slot] = key;
      }
    }
    __syncthreads();
    const int cnt = min(s_cnt, CANDCAP);
    for (int i = tid; i < CANDCAP; i += NT_SEL)
      if (i >= cnt) cand[i] = 0ull;
    bitonic1024_desc(cand, tid);       // starts with its own __syncthreads
    for (int i = tid; i < kk; i += NT_SEL) sel[sbase + i] = cand[i];
    __syncthreads();
  }

  // --- per-slot outputs ---
  if (tid < TT) {
    const int j = tid;
    const bool isp = j < pos_count;
    const bool isn = !isp && (j < pos_count + neg_count);
    float c0 = 0.f, c1 = 0.f, d0 = 0.f, d1 = 0.f, d2 = 0.f, d3 = 0.f;
    int out_idx = -1, tag = -1;
    if (isp) {
      const unsigned long long key = sel[j];
      const int a = (int)((((unsigned)(key >> 6)) & 0x3FFFFu) ^ 0x3FFFFu);
      const int g = (int)(key & 63ull);
      out_idx = a; tag = 1;
      c0 = s_cls0[g]; c1 = s_cls1[g];
      float4 an = ((const float4*)anchors)[(size_t)b * AA + a];
      float4 gb = s_gt[g];
      float h = an.z - an.x, w = an.w - an.y;
      float gh = gb.z - gb.x, gw = gb.w - gb.y;
      float cy = (an.z + an.x) * 0.5f, cx = (an.w + an.y) * 0.5f;
      float gcy = (gb.z + gb.x) * 0.5f, gcx = (gb.w + gb.y) * 0.5f;
      d0 = ((gcy - cy) / h) / 0.1f;
      d1 = ((gcx - cx) / w) / 0.1f;
      d2 = logf(gh / h) / 0.2f;
      d3 = logf(gw / w) / 0.2f;
      if (g < 32) atomicOr(&hit_lo, 1u << g);
      else        atomicOr(&hit_hi, 1u << (g - 32));
    } else if (isn) {
      const unsigned long long key = sel[j];
      out_idx = (int)((((unsigned)(key >> 6)) & 0x3FFFFu) ^ 0x3FFFFu);
      tag = 0;
      c0 = 1.f; c1 = 0.f;
    }

    float* cls_out = out + ((size_t)b * TT + j) * 2;
    cls_out[0] = c0; cls_out[1] = c1;
    float* del_out = out + 2048 + ((size_t)b * TT + j) * 4;
    del_out[0] = d0; del_out[1] = d1; del_out[2] = d2; del_out[3] = d3;
    float* idx_out = out + 6144 + ((size_t)b * TT + j) * 2;
    idx_out[0] = (float)out_idx; idx_out[1] = (float)tag;
  }

  __syncthreads();
  if (tid == 0) {
    int gn = 0;
    for (int g = 0; g < GG; ++g) gn += s_valid[g];
    float hits = (float)(__popc(hit_lo) + __popc(hit_hi));
    out[8192 + b] = (float)gn;
    out[8196 + b] = (float)pos_count;
    out[8200 + b] = (float)gn - hits;
  }
}

// ---------------- host ----------------
extern "C" void kernel_launch(void* const* d_in, const int* in_sizes, int n_in,
                              void* d_out, int out_size, void* d_ws, size_t ws_size,
                              hipStream_t stream) {
  const float* gt_boxes = (const float*)d_in[0];
  const float* gt_cls   = (const float*)d_in[1];
  const float* anchors  = (const float*)d_in[2];
  float* out = (float*)d_out;

  // folded keys: key(42) = (0,42); fold_in(k, d) = threefry block on (0, d)
  uint32_t kp0, kp1, kn0, kn1;
  tf2x32(0u, 42u, 0u, 0u, kp0, kp1);   // pri_pos key
  tf2x32(0u, 42u, 0u, 1u, kn0, kn1);   // pri_neg key

  // ws layout: [256B counters][pos_key B*cap_pos*8][neg_key B*cap_neg*8]
  long cap_pos = 32768, cap_neg = 8192;
  while (cap_pos > 2048 &&
         256 + (size_t)BB * 8 * (size_t)(cap_pos + cap_neg) > ws_size) {
    cap_pos >>= 1; cap_neg >>= 1;
  }
  char* base = (char*)d_ws;
  int* counters = (int*)base;
  unsigned long long* pos_key = (unsigned long long*)(base + 256);
  unsigned long long* neg_key = pos_key + (size_t)BB * cap_pos;

  hipMemsetAsync(d_ws, 0, 256, stream);
  k_scan<<<BB * (AA / BLK_ANCH), SCAN_NT, 0, stream>>>(
      gt_boxes, gt_cls, anchors, counters, pos_key, neg_key,
      (int)cap_pos, (int)cap_neg, kp0, kp1, kn0, kn1);
  k_select<<<BB, NT_SEL, 0, stream>>>(
      gt_boxes, gt_cls, anchors, counters, pos_key, neg_key,
      (int)cap_pos, (int)cap_neg, out);
}